// Round 9
// baseline (553.429 us; speedup 1.0000x reference)
//
#include <hip/hip_runtime.h>
#include <hip/hip_bf16.h>

#define BATCH 4096
#define NTOT  8192
#define DIM   512
#define NBLK  528   // triangle over 32x32 grid of 256-tiles

typedef __attribute__((ext_vector_type(8))) __bf16 bf16x8;
typedef __attribute__((ext_vector_type(4))) float  floatx4;

__device__ __forceinline__ unsigned short f2bf(float x) {
  union { float f; unsigned u; } v; v.f = x;
  unsigned r = v.u + 0x7fffu + ((v.u >> 16) & 1u);   // RNE
  return (unsigned short)(r >> 16);
}

#define ASYNC16(gp, lp)                                                        \
  __builtin_amdgcn_global_load_lds(                                            \
      (__attribute__((address_space(1))) void*)(gp),                           \
      (__attribute__((address_space(3))) void*)(lp), 16, 0, 0)

// ---------------------------------------------------------------- normalize
// One wave per row: read 512 fp32, rsqrt(sum sq), write 512 bf16.
// Blocks 0..31 also zero S; block 32 zeroes out[0] (loss accumulates into it).
__global__ __launch_bounds__(256) void nrm_kernel(const float* __restrict__ zi,
                                                  const float* __restrict__ zj,
                                                  ushort* __restrict__ zn,
                                                  float* __restrict__ S,
                                                  float* __restrict__ out) {
  if (blockIdx.x < 32) S[blockIdx.x * 256 + threadIdx.x] = 0.0f;
  if (blockIdx.x == 32 && threadIdx.x == 0) out[0] = 0.0f;
  const int row = blockIdx.x * 4 + (threadIdx.x >> 6);
  const int l   = threadIdx.x & 63;
  const float* src = (row < BATCH) ? (zi + (size_t)row * DIM)
                                   : (zj + (size_t)(row - BATCH) * DIM);
  const float4* s4 = (const float4*)src;
  float4 v0 = s4[l];
  float4 v1 = s4[l + 64];
  float ss = v0.x*v0.x + v0.y*v0.y + v0.z*v0.z + v0.w*v0.w
           + v1.x*v1.x + v1.y*v1.y + v1.z*v1.z + v1.w*v1.w;
  #pragma unroll
  for (int m = 1; m < 64; m <<= 1) ss += __shfl_xor(ss, m, 64);
  const float r = 1.0f / fmaxf(sqrtf(ss), 1e-12f);
  ushort4 o0, o1;
  o0.x = f2bf(v0.x * r); o0.y = f2bf(v0.y * r);
  o0.z = f2bf(v0.z * r); o0.w = f2bf(v0.w * r);
  o1.x = f2bf(v1.x * r); o1.y = f2bf(v1.y * r);
  o1.z = f2bf(v1.z * r); o1.w = f2bf(v1.w * r);
  ushort4* d4 = (ushort4*)(zn + (size_t)row * DIM);
  d4[l]      = o0;
  d4[l + 64] = o1;
}

// ---------------------------------------------------------------- main GEMM
// 256x256 block tile, 512 threads (8 waves, 2x4 wave grid), per-wave output
// 128x64, BK=32, R5's proven 2-buffer/one-__syncthreads shell.
// R8 lesson (pinned): __launch_bounds__(512, 2) caused accumulator spill
// (effective 128-reg/wave cap -> acc[8][4] alone = 128 VGPRs -> 2.29 GB
// scratch writes, 490us). MUST be (512, 1): one 8-wave block/CU, 256
// regs/wave, ~210 live fits. Geometry itself refchecked OK in R8 (absmax 0).
// WHY 256²/128x64-per-wave (R7 post-mortem): LDS-BW bound. FLOP per
// LDS-read-byte set by per-wave tile: 64x64 -> 32 FLOP/B caps MfmaUtil ~25%;
// 128x64 -> 42.7 FLOP/B (m201 geometry): 12 ds_read_b128 feed 32 MFMA per
// wave-iter. Also halves L2-side staging traffic per FLOP (532->270 MB).
// LDS swizzle: R0's verified scheme: k-chunk c of row r at slot c^((r>>1)&3);
// staging sources pre-swizzled globals, LDS dest linear (global_load_lds).
// Lessons pinned: NO fused loss tail (+15us R3/R4); NO agent ACQ_REL (+25us
// R1/R2); NO XCD swizzle (wrong regime); NO sched_barrier pinning (R1/m141);
// depth-2 prefetch null (R6); BK=64 regression (R7).
__global__ __launch_bounds__(512, 1) void simsum_kernel(const ushort* __restrict__ zn,
                                                        float* __restrict__ S,
                                                        float* __restrict__ P) {
  // triangle decode: u = bj*(bj+1)/2 + bi, bi <= bj < 32
  const int u = blockIdx.x;
  int bj = (int)((sqrtf(8.0f * (float)u + 1.0f) - 1.0f) * 0.5f);
  while ((bj + 1) * (bj + 2) / 2 <= u) ++bj;
  while (bj * (bj + 1) / 2 > u) --bj;
  const int bi = u - bj * (bj + 1) / 2;
  const bool diag = (bi == bj);
  const bool posb = (bj == bi + BATCH / 256);

  __shared__ __align__(16) ushort shA[2 * 8192];  // 2 buf x 256 rows x 32 k
  __shared__ __align__(16) ushort shB[2 * 8192];
  __shared__ float redR[4][256];
  __shared__ float redC[2][256];

  const int t    = threadIdx.x;
  const int w    = t >> 6;          // 0..7
  const int l    = t & 63;
  const int quad = l >> 4;
  const int lo   = l & 15;
  const int wm   = w >> 2;          // 0..1 : row half (128 rows)
  const int wn   = w & 3;           // 0..3 : col quarter (64 cols)
  const int tileRow = bi * 256;
  const int tileCol = bj * 256;

  // staging: thread (w,l) stages chunks c0 = w*128+l and c1 = c0+64 (16B
  // each) of A and of B. 1024 chunks = 256 rows x 4 slots. Chunk p ->
  // row r = p>>2, slot s = p&3, content k-chunk c = s ^ ((r>>1)&3)
  // (inverse XOR applied on the global source; LDS dest linear).
  const int c0 = w * 128 + l;
  const int c1 = c0 + 64;
  const int r0 = c0 >> 2, k0 = ((c0 & 3) ^ ((r0 >> 1) & 3)) * 8;
  const int r1 = c1 >> 2, k1 = ((c1 & 3) ^ ((r1 >> 1) & 3)) * 8;
  const ushort* gA0 = zn + (size_t)(tileRow + r0) * DIM + k0;
  const ushort* gA1 = zn + (size_t)(tileRow + r1) * DIM + k1;
  const ushort* gB0 = zn + (size_t)(tileCol + r0) * DIM + k0;
  const ushort* gB1 = zn + (size_t)(tileCol + r1) * DIM + k1;
  ushort* lA0 = shA + w * 1024;            // chunk c0 base (ushorts), +l*8
  ushort* lA1 = shA + w * 1024 + 512;
  ushort* lB0 = shB + w * 1024;
  ushort* lB1 = shB + w * 1024 + 512;

  floatx4 acc[8][4];
  #pragma unroll
  for (int i = 0; i < 8; ++i)
    #pragma unroll
    for (int j = 0; j < 4; ++j)
      acc[i][j] = (floatx4){0.f, 0.f, 0.f, 0.f};

  // fragment reads: row stride 32 ushorts; slot = quad ^ ((lo>>1)&3).
  const int sw   = (quad ^ ((lo >> 1) & 3)) * 8;
  const int aOff = (wm * 128 + lo) * 32 + sw;  // + i*512 (16 rows)
  const int bOff = (wn * 64 + lo) * 32 + sw;   // + j*512

  #define STAGE(bufo)                                                         \
    ASYNC16(gA0, lA0 + (bufo)); ASYNC16(gA1, lA1 + (bufo));                   \
    ASYNC16(gB0, lB0 + (bufo)); ASYNC16(gB1, lB1 + (bufo));                   \
    gA0 += 32; gA1 += 32; gB0 += 32; gB1 += 32;

  // prologue: stage K-tile 0 into buffer 0
  STAGE(0)

  #pragma unroll
  for (int it = 0; it < 16; ++it) {
    __syncthreads();  // drains loads for buffer `cur` (issued one iter ago)
    const int co = (it & 1) * 8192;
    const int no = co ^ 8192;
    if (it < 15) { STAGE(no) }
    bf16x8 aF[8], bF[4];
    #pragma unroll
    for (int i = 0; i < 8; ++i) aF[i] = *(const bf16x8*)(shA + co + aOff + i * 512);
    #pragma unroll
    for (int j = 0; j < 4; ++j) bF[j] = *(const bf16x8*)(shB + co + bOff + j * 512);
    #pragma unroll
    for (int i = 0; i < 8; ++i)
      #pragma unroll
      for (int j = 0; j < 4; ++j)
        acc[i][j] = __builtin_amdgcn_mfma_f32_16x16x32_bf16(aF[i], bF[j],
                                                            acc[i][j], 0, 0, 0);
  }
  #undef STAGE

  // ---- epilogue. C/D layout: col = lo, row = quad*4 + r (within 16x16)
  float rs[8][4];
  float cs[4];
  #pragma unroll
  for (int i = 0; i < 8; ++i)
    #pragma unroll
    for (int r = 0; r < 4; ++r) rs[i][r] = 0.f;
  #pragma unroll
  for (int j = 0; j < 4; ++j) cs[j] = 0.f;

  #pragma unroll
  for (int i = 0; i < 8; ++i)
    #pragma unroll
    for (int j = 0; j < 4; ++j)
      #pragma unroll
      for (int r = 0; r < 4; ++r) {
        const float e = __expf(acc[i][j][r] * 10.0f - 10.0f);
        rs[i][r] += e;
        cs[j] += e;
      }

  // diagonal-crossing waves: d = wn - 2*wm in {0,1}; local diag at
  // i == d*4 + j, lanes with quad == lo>>2 (i.e. local row off == col off).
  const int d = wn - 2 * wm;
  if ((d == 0 || d == 1) && quad == (lo >> 2)) {
    const int r = lo & 3;
    if (diag) {  // self-similarity: remove exp from both row and col sums
      #pragma unroll
      for (int j = 0; j < 4; ++j) {
        const int i = d * 4 + j;
        const float e = __expf(acc[i][j][r] * 10.0f - 10.0f);
        rs[i][r] -= e;
        cs[j] -= e;
      }
    }
    if (posb) {  // positives: col == row + BATCH
      #pragma unroll
      for (int j = 0; j < 4; ++j) {
        const int i = d * 4 + j;
        const int row = tileRow + wm * 128 + i * 16 + lo;
        const float v = acc[i][j][r] * 10.0f;
        P[row] = v;
        P[row + BATCH] = v;
      }
    }
  }

  // row sums: reduce across the 16 column-lanes (low 4 lane bits)
  #pragma unroll
  for (int m = 1; m < 16; m <<= 1) {
    #pragma unroll
    for (int i = 0; i < 8; ++i)
      #pragma unroll
      for (int r = 0; r < 4; ++r)
        rs[i][r] += __shfl_xor(rs[i][r], m, 64);
  }
  if (lo == 0) {
    #pragma unroll
    for (int i = 0; i < 8; ++i)
      #pragma unroll
      for (int r = 0; r < 4; ++r)
        redR[wn][wm * 128 + i * 16 + quad * 4 + r] = rs[i][r];
  }
  // col sums: reduce across the 4 quads (lane bits 4,5)
  #pragma unroll
  for (int m = 16; m < 64; m <<= 1) {
    #pragma unroll
    for (int j = 0; j < 4; ++j) cs[j] += __shfl_xor(cs[j], m, 64);
  }
  if (quad == 0) {
    #pragma unroll
    for (int j = 0; j < 4; ++j)
      redC[wm][wn * 64 + j * 16 + lo] = cs[j];
  }
  __syncthreads();
  if (t < 256) {
    atomicAdd(&S[tileRow + t],
              redR[0][t] + redR[1][t] + redR[2][t] + redR[3][t]);
  } else if (!diag) {
    const int c = t - 256;
    atomicAdd(&S[tileCol + c], redC[0][c] + redC[1][c]);
  }
  // waves retire here, fire-and-forget on the atomics (no drain — critical).
}

// ---------------------------------------------------------------- final loss
// 32 blocks x 256 threads, 1 element/thread; partial per block, one float
// atomicAdd into out[0] (zeroed by nrm).
__global__ __launch_bounds__(256) void loss_kernel(const float* __restrict__ S,
                                                   const float* __restrict__ P,
                                                   float* __restrict__ out) {
  const int i = blockIdx.x * 256 + threadIdx.x;
  float a = 10.0f + logf(S[i]) - P[i];
  #pragma unroll
  for (int m = 1; m < 64; m <<= 1) a += __shfl_xor(a, m, 64);
  __shared__ float sb[4];
  if ((threadIdx.x & 63) == 0) sb[threadIdx.x >> 6] = a;
  __syncthreads();
  if (threadIdx.x == 0)
    atomicAdd(out, (sb[0] + sb[1] + sb[2] + sb[3]) * (1.0f / (float)NTOT));
}

extern "C" void kernel_launch(void* const* d_in, const int* in_sizes, int n_in,
                              void* d_out, int out_size, void* d_ws, size_t ws_size,
                              hipStream_t stream) {
  const float* zi = (const float*)d_in[0];
  const float* zj = (const float*)d_in[1];
  ushort* zn = (ushort*)d_ws;                                  // 8192*512 bf16 = 8 MB
  float*  S  = (float*)((char*)d_ws + (size_t)NTOT * DIM * 2); // 32 KB
  float*  P  = S + NTOT;                                       // 32 KB
  float*  out = (float*)d_out;

  nrm_kernel<<<NTOT / 4, 256, 0, stream>>>(zi, zj, zn, S, out);
  simsum_kernel<<<NBLK, 512, 0, stream>>>(zn, S, P);
  loss_kernel<<<NTOT / 256, 256, 0, stream>>>(S, P, out);
}

// Round 10
// 127.822 us; speedup vs baseline: 4.3297x; 4.3297x over previous
//
#include <hip/hip_runtime.h>
#include <hip/hip_bf16.h>

#define BATCH 4096
#define NTOT  8192
#define DIM   512
#define NBLK  528   // triangle over 32x32 grid of 256-tiles

typedef __attribute__((ext_vector_type(8))) __bf16 bf16x8;
typedef __attribute__((ext_vector_type(4))) float  floatx4;

__device__ __forceinline__ unsigned short f2bf(float x) {
  union { float f; unsigned u; } v; v.f = x;
  unsigned r = v.u + 0x7fffu + ((v.u >> 16) & 1u);   // RNE
  return (unsigned short)(r >> 16);
}

#define ASYNC16(gp, lp)                                                        \
  __builtin_amdgcn_global_load_lds(                                            \
      (__attribute__((address_space(1))) void*)(gp),                           \
      (__attribute__((address_space(3))) void*)(lp), 16, 0, 0)

// ---------------------------------------------------------------- normalize
// One wave per row: read 512 fp32, rsqrt(sum sq), write 512 bf16.
// Blocks 0..31 also zero S; block 32 zeroes out[0] (loss accumulates into it).
__global__ __launch_bounds__(256) void nrm_kernel(const float* __restrict__ zi,
                                                  const float* __restrict__ zj,
                                                  ushort* __restrict__ zn,
                                                  float* __restrict__ S,
                                                  float* __restrict__ out) {
  if (blockIdx.x < 32) S[blockIdx.x * 256 + threadIdx.x] = 0.0f;
  if (blockIdx.x == 32 && threadIdx.x == 0) out[0] = 0.0f;
  const int row = blockIdx.x * 4 + (threadIdx.x >> 6);
  const int l   = threadIdx.x & 63;
  const float* src = (row < BATCH) ? (zi + (size_t)row * DIM)
                                   : (zj + (size_t)(row - BATCH) * DIM);
  const float4* s4 = (const float4*)src;
  float4 v0 = s4[l];
  float4 v1 = s4[l + 64];
  float ss = v0.x*v0.x + v0.y*v0.y + v0.z*v0.z + v0.w*v0.w
           + v1.x*v1.x + v1.y*v1.y + v1.z*v1.z + v1.w*v1.w;
  #pragma unroll
  for (int m = 1; m < 64; m <<= 1) ss += __shfl_xor(ss, m, 64);
  const float r = 1.0f / fmaxf(sqrtf(ss), 1e-12f);
  ushort4 o0, o1;
  o0.x = f2bf(v0.x * r); o0.y = f2bf(v0.y * r);
  o0.z = f2bf(v0.z * r); o0.w = f2bf(v0.w * r);
  o1.x = f2bf(v1.x * r); o1.y = f2bf(v1.y * r);
  o1.z = f2bf(v1.z * r); o1.w = f2bf(v1.w * r);
  ushort4* d4 = (ushort4*)(zn + (size_t)row * DIM);
  d4[l]      = o0;
  d4[l + 64] = o1;
}

// ---------------------------------------------------------------- main GEMM
// 256x256 block tile, 512 threads (8 waves, 2x4 wave grid), per-wave output
// 128x64, BK=32, R5's proven 2-buffer/one-__syncthreads shell.
// R9 lesson (pinned, rule #20): the diag/posb epilogue indexed acc with a
// RUNTIME array index (i = d*4+j, d = wn-2*wm) -> whole acc[8][4] allocated
// in scratch -> 2.29 GB spill traffic, 490us, MfmaUtil 2.8% (R8+R9; the
// launch-bounds change in R9 was a null fix, counters identical). Epilogue
// must use STATIC indices with runtime predicates. Runtime VECTOR-lane index
// [r] is fine (select chain; proven since R0).
// WHY 256²/128x64-per-wave (R7): LDS-BW bound; FLOP/LDS-byte set by wave
// tile: 64x64 -> 32 FLOP/B caps ~25% MfmaUtil; 128x64 -> 42.7 (m201 geom).
// Lessons pinned: NO fused loss tail (+15us R3/R4); NO agent ACQ_REL (+25us
// R1/R2); NO XCD swizzle (wrong regime); NO sched_barrier pinning (R1/m141);
// depth-2 prefetch null (R6); BK=64 regression (R7).
__global__ __launch_bounds__(512, 1) void simsum_kernel(const ushort* __restrict__ zn,
                                                        float* __restrict__ S,
                                                        float* __restrict__ P) {
  // triangle decode: u = bj*(bj+1)/2 + bi, bi <= bj < 32
  const int u = blockIdx.x;
  int bj = (int)((sqrtf(8.0f * (float)u + 1.0f) - 1.0f) * 0.5f);
  while ((bj + 1) * (bj + 2) / 2 <= u) ++bj;
  while (bj * (bj + 1) / 2 > u) --bj;
  const int bi = u - bj * (bj + 1) / 2;
  const bool diag = (bi == bj);
  const bool posb = (bj == bi + BATCH / 256);

  __shared__ __align__(16) ushort shA[2 * 8192];  // 2 buf x 256 rows x 32 k
  __shared__ __align__(16) ushort shB[2 * 8192];
  __shared__ float redR[4][256];
  __shared__ float redC[2][256];

  const int t    = threadIdx.x;
  const int w    = t >> 6;          // 0..7
  const int l    = t & 63;
  const int quad = l >> 4;
  const int lo   = l & 15;
  const int wm   = w >> 2;          // 0..1 : row half (128 rows)
  const int wn   = w & 3;           // 0..3 : col quarter (64 cols)
  const int tileRow = bi * 256;
  const int tileCol = bj * 256;

  // staging: thread (w,l) stages chunks c0 = w*128+l and c1 = c0+64 (16B
  // each) of A and of B. 1024 chunks = 256 rows x 4 slots. Chunk p ->
  // row r = p>>2, slot s = p&3, content k-chunk c = s ^ ((r>>1)&3)
  // (inverse XOR applied on the global source; LDS dest linear).
  const int c0 = w * 128 + l;
  const int c1 = c0 + 64;
  const int r0 = c0 >> 2, k0 = ((c0 & 3) ^ ((r0 >> 1) & 3)) * 8;
  const int r1 = c1 >> 2, k1 = ((c1 & 3) ^ ((r1 >> 1) & 3)) * 8;
  const ushort* gA0 = zn + (size_t)(tileRow + r0) * DIM + k0;
  const ushort* gA1 = zn + (size_t)(tileRow + r1) * DIM + k1;
  const ushort* gB0 = zn + (size_t)(tileCol + r0) * DIM + k0;
  const ushort* gB1 = zn + (size_t)(tileCol + r1) * DIM + k1;
  ushort* lA0 = shA + w * 1024;            // chunk c0 base (ushorts), +l*8
  ushort* lA1 = shA + w * 1024 + 512;
  ushort* lB0 = shB + w * 1024;
  ushort* lB1 = shB + w * 1024 + 512;

  floatx4 acc[8][4];
  #pragma unroll
  for (int i = 0; i < 8; ++i)
    #pragma unroll
    for (int j = 0; j < 4; ++j)
      acc[i][j] = (floatx4){0.f, 0.f, 0.f, 0.f};

  // fragment reads: row stride 32 ushorts; slot = quad ^ ((lo>>1)&3).
  const int sw   = (quad ^ ((lo >> 1) & 3)) * 8;
  const int aOff = (wm * 128 + lo) * 32 + sw;  // + i*512 (16 rows)
  const int bOff = (wn * 64 + lo) * 32 + sw;   // + j*512

  #define STAGE(bufo)                                                         \
    ASYNC16(gA0, lA0 + (bufo)); ASYNC16(gA1, lA1 + (bufo));                   \
    ASYNC16(gB0, lB0 + (bufo)); ASYNC16(gB1, lB1 + (bufo));                   \
    gA0 += 32; gA1 += 32; gB0 += 32; gB1 += 32;

  // prologue: stage K-tile 0 into buffer 0
  STAGE(0)

  #pragma unroll
  for (int it = 0; it < 16; ++it) {
    __syncthreads();  // drains loads for buffer `cur` (issued one iter ago)
    const int co = (it & 1) * 8192;
    const int no = co ^ 8192;
    if (it < 15) { STAGE(no) }
    bf16x8 aF[8], bF[4];
    #pragma unroll
    for (int i = 0; i < 8; ++i) aF[i] = *(const bf16x8*)(shA + co + aOff + i * 512);
    #pragma unroll
    for (int j = 0; j < 4; ++j) bF[j] = *(const bf16x8*)(shB + co + bOff + j * 512);
    #pragma unroll
    for (int i = 0; i < 8; ++i)
      #pragma unroll
      for (int j = 0; j < 4; ++j)
        acc[i][j] = __builtin_amdgcn_mfma_f32_16x16x32_bf16(aF[i], bF[j],
                                                            acc[i][j], 0, 0, 0);
  }
  #undef STAGE

  // ---- epilogue. C/D layout: col = lo, row = quad*4 + r (within 16x16)
  float rs[8][4];
  float cs[4];
  #pragma unroll
  for (int i = 0; i < 8; ++i)
    #pragma unroll
    for (int r = 0; r < 4; ++r) rs[i][r] = 0.f;
  #pragma unroll
  for (int j = 0; j < 4; ++j) cs[j] = 0.f;

  #pragma unroll
  for (int i = 0; i < 8; ++i)
    #pragma unroll
    for (int j = 0; j < 4; ++j)
      #pragma unroll
      for (int r = 0; r < 4; ++r) {
        const float e = __expf(acc[i][j][r] * 10.0f - 10.0f);
        rs[i][r] += e;
        cs[j] += e;
      }

  // diagonal-crossing waves: d = wn - 2*wm in {0,1}; local diag at
  // i == d*4 + j, lanes with quad == lo>>2. STATIC ii loop + runtime
  // predicate (rule #20: runtime array index would force acc to scratch).
  const int d = wn - 2 * wm;
  if ((d == 0 || d == 1) && quad == (lo >> 2)) {
    const int r = lo & 3;   // runtime VECTOR-lane index: OK (select chain)
    #pragma unroll
    for (int ii = 0; ii < 8; ++ii)
      #pragma unroll
      for (int j = 0; j < 4; ++j)
        if (ii == d * 4 + j) {  // runtime predicate, static indices
          if (diag) {  // self-similarity: remove exp from row and col sums
            const float e = __expf(acc[ii][j][r] * 10.0f - 10.0f);
            rs[ii][r] -= e;
            cs[j] -= e;
          }
          if (posb) {  // positives: col == row + BATCH
            const int row = tileRow + wm * 128 + ii * 16 + lo;
            const float v = acc[ii][j][r] * 10.0f;
            P[row] = v;
            P[row + BATCH] = v;
          }
        }
  }

  // row sums: reduce across the 16 column-lanes (low 4 lane bits)
  #pragma unroll
  for (int m = 1; m < 16; m <<= 1) {
    #pragma unroll
    for (int i = 0; i < 8; ++i)
      #pragma unroll
      for (int r = 0; r < 4; ++r)
        rs[i][r] += __shfl_xor(rs[i][r], m, 64);
  }
  if (lo == 0) {
    #pragma unroll
    for (int i = 0; i < 8; ++i)
      #pragma unroll
      for (int r = 0; r < 4; ++r)
        redR[wn][wm * 128 + i * 16 + quad * 4 + r] = rs[i][r];
  }
  // col sums: reduce across the 4 quads (lane bits 4,5)
  #pragma unroll
  for (int m = 16; m < 64; m <<= 1) {
    #pragma unroll
    for (int j = 0; j < 4; ++j) cs[j] += __shfl_xor(cs[j], m, 64);
  }
  if (quad == 0) {
    #pragma unroll
    for (int j = 0; j < 4; ++j)
      redC[wm][wn * 64 + j * 16 + lo] = cs[j];
  }
  __syncthreads();
  if (t < 256) {
    atomicAdd(&S[tileRow + t],
              redR[0][t] + redR[1][t] + redR[2][t] + redR[3][t]);
  } else if (!diag) {
    const int c = t - 256;
    atomicAdd(&S[tileCol + c], redC[0][c] + redC[1][c]);
  }
  // waves retire here, fire-and-forget on the atomics (no drain — critical).
}

// ---------------------------------------------------------------- final loss
// 32 blocks x 256 threads, 1 element/thread; partial per block, one float
// atomicAdd into out[0] (zeroed by nrm).
__global__ __launch_bounds__(256) void loss_kernel(const float* __restrict__ S,
                                                   const float* __restrict__ P,
                                                   float* __restrict__ out) {
  const int i = blockIdx.x * 256 + threadIdx.x;
  float a = 10.0f + logf(S[i]) - P[i];
  #pragma unroll
  for (int m = 1; m < 64; m <<= 1) a += __shfl_xor(a, m, 64);
  __shared__ float sb[4];
  if ((threadIdx.x & 63) == 0) sb[threadIdx.x >> 6] = a;
  __syncthreads();
  if (threadIdx.x == 0)
    atomicAdd(out, (sb[0] + sb[1] + sb[2] + sb[3]) * (1.0f / (float)NTOT));
}

extern "C" void kernel_launch(void* const* d_in, const int* in_sizes, int n_in,
                              void* d_out, int out_size, void* d_ws, size_t ws_size,
                              hipStream_t stream) {
  const float* zi = (const float*)d_in[0];
  const float* zj = (const float*)d_in[1];
  ushort* zn = (ushort*)d_ws;                                  // 8192*512 bf16 = 8 MB
  float*  S  = (float*)((char*)d_ws + (size_t)NTOT * DIM * 2); // 32 KB
  float*  P  = S + NTOT;                                       // 32 KB
  float*  out = (float*)d_out;

  nrm_kernel<<<NTOT / 4, 256, 0, stream>>>(zi, zj, zn, S, out);
  simsum_kernel<<<NBLK, 512, 0, stream>>>(zn, S, P);
  loss_kernel<<<NTOT / 256, 256, 0, stream>>>(S, P, out);
}